// Round 9
// baseline (791.036 us; speedup 1.0000x reference)
//
#include <hip/hip_runtime.h>

#define HDIM  64
#define INDIM 7
#define QDIM  3
#define TDEC  288
#define SEQ   512
#define NB    4        // batches per block (grid 512, 2 blocks/CU)
#define CHUNK 32       // x timesteps staged per LDS chunk
#define HPAD  68       // fp32 h/c row stride (decoder handoff)
#define GPAD  264      // lds_g row stride (decoder gbase only)
#define HBST  80       // bf16 h row stride in shorts (160B)

typedef __attribute__((ext_vector_type(8))) short bf16x8;   // 8 bf16 in 4 VGPRs
typedef __attribute__((ext_vector_type(4))) short bf16x4;   // 4 bf16 in 2 VGPRs
typedef __attribute__((ext_vector_type(4))) float f32x4;

__device__ __forceinline__ float fast_rcp(float x) { return __builtin_amdgcn_rcpf(x); }
__device__ __forceinline__ float sigm(float x) { return fast_rcp(1.0f + __expf(-x)); }
__device__ __forceinline__ float tanh_f(float x) {
    float xx = fminf(fmaxf(x, -15.0f), 15.0f);
    float e = __expf(2.0f * xx);
    return (e - 1.0f) * fast_rcp(e + 1.0f);
}
// round-to-nearest-even fp32 -> bf16 bits
__device__ __forceinline__ short f2bf(float f) {
    union { float f; unsigned u; } v; v.f = f;
    unsigned r = (v.u + 0x7fffu + ((v.u >> 16) & 1u)) >> 16;
    return (short)r;
}
__device__ __forceinline__ float bf2f(short s) {
    union { unsigned u; float f; } v; v.u = ((unsigned)(unsigned short)s) << 16;
    return v.f;
}

// R9: in-register activation + x/bias folded into MFMA K-dim.
// Wave wid owns units [16*wid, 16*wid+16). A-frags: rows g*64+wid*16+(lane&15),
// K = [h(64) | x(7) | 1(bias-slot)]. B cols replicate batches mod 4, so EVERY
// lane's acc[g][r] = pre-activation of gate g for (b=lane&3,
// u=wid*16+(lane>>4)*4+r): act runs fully in-register, writer lanes
// ((lane&12)==0) publish h as b64 hi + b64 lo. One barrier per step,
// h parity-double-buffered. 3-pass hi/lo MFMA (~fp32 precision) throughout.
__global__ __launch_bounds__(256, 2)
void enc_dec_kernel(const float* __restrict__ x,
                    const float* __restrict__ eWih, const float* __restrict__ eWhh,
                    const float* __restrict__ ebih, const float* __restrict__ ebhh,
                    const float* __restrict__ dWih, const float* __restrict__ dWhh,
                    const float* __restrict__ dbih, const float* __restrict__ dbhh,
                    const float* __restrict__ oW,   const float* __restrict__ obv,
                    float* __restrict__ out)
{
    __shared__ __align__(16) short lds_hhi[2][NB][HBST];   // h hi bf16, parity dbuf
    __shared__ __align__(16) short lds_hlo[2][NB][HBST];   // h lo bf16
    __shared__ __align__(16) short lds_xbh[2][CHUNK][NB][8]; // x hi bf16 (k=0..6, k7=1.0)
    __shared__ __align__(16) short lds_xbl[2][CHUNK][NB][8]; // x lo bf16
    __shared__ __align__(16) short lds_xzero[8];             // zero stub for g16>0 reads
    __shared__ __align__(16) float lds_hf[NB][HPAD];       // fp32 h_enc (final step)
    __shared__ __align__(16) float lds_cf[NB][HPAD];       // fp32 c_enc (final step)
    __shared__ __align__(16) float lds_g[NB][GPAD];        // decoder gbase staging

    const int tid  = threadIdx.x;
    const int lane = tid & 63;
    const int wid  = tid >> 6;
    const int b0   = blockIdx.x * NB;

    const int m    = lane & 15;           // A-row within tile / D n-col
    const int g16  = lane >> 4;           // k-subblock (A/B) and D row-quad
    const int bcol = lane & 3;            // batch of this lane's D column
    const int u0   = wid * 16 + g16 * 4;  // first unit of this lane's D row-quad

    // ---- A fragments: [gate][kt]; kt=0,1 Whh; kt=2 = [Wih | bias] (g16==0 only) ----
    bf16x8 a_hi[4][3], a_lo[4][3];
#pragma unroll
    for (int g = 0; g < 4; ++g) {
        const int row = g * 64 + wid * 16 + m;
#pragma unroll
        for (int kt = 0; kt < 2; ++kt) {
            const float* p = eWhh + (size_t)row * HDIM + kt * 32 + g16 * 8;
            f32x4 v0 = *(const f32x4*)p;
            f32x4 v1 = *(const f32x4*)(p + 4);
#pragma unroll
            for (int e = 0; e < 4; ++e) {
                short hi = f2bf(v0[e]);
                a_hi[g][kt][e] = hi;
                a_lo[g][kt][e] = f2bf(v0[e] - bf2f(hi));
            }
#pragma unroll
            for (int e = 0; e < 4; ++e) {
                short hi = f2bf(v1[e]);
                a_hi[g][kt][4 + e] = hi;
                a_lo[g][kt][4 + e] = f2bf(v1[e] - bf2f(hi));
            }
        }
        if (g16 == 0) {
#pragma unroll
            for (int e = 0; e < 8; ++e) {
                float v = (e < 7) ? eWih[row * INDIM + e] : (ebih[row] + ebhh[row]);
                short hi = f2bf(v);
                a_hi[g][2][e] = hi;
                a_lo[g][2][e] = f2bf(v - bf2f(hi));
            }
        } else {
#pragma unroll
            for (int e = 0; e < 8; ++e) { a_hi[g][2][e] = 0; a_lo[g][2][e] = 0; }
        }
    }

    // ---- init: h parity[1] = 0 (step 0 reads it); zero stub ----
    { int b = tid >> 6, u = tid & 63; lds_hhi[1][b][u] = 0; lds_hlo[1][b][u] = 0; }
    if (tid < 8) lds_xzero[tid] = 0;
    float c_reg[4] = {0.0f, 0.0f, 0.0f, 0.0f};

    // ---- load x chunk 0 (bf16 hi/lo split; k==7 slot = 1.0 for bias) ----
    for (int i = tid; i < NB * CHUNK * 8; i += 256) {
        int b = i >> 8;          // CHUNK*8 == 256
        int r = i & 255;
        int s = r >> 3;
        int k = r & 7;
        float v = (k < 7) ? x[((size_t)(b0 + b) * SEQ + s) * INDIM + k] : 1.0f;
        short hi = f2bf(v);
        lds_xbh[0][s][b][k] = hi;
        lds_xbl[0][s][b][k] = f2bf(v - bf2f(hi));
    }
    __syncthreads();

    // ================= encoder: 512 serial steps, ONE barrier each =================
    for (int s = 0; s < SEQ; ++s) {
        const int cs  = s & (CHUNK - 1);
        const int buf = (s >> 5) & 1;
        const int rb  = (s & 1) ^ 1;   // h read-parity
        const int wb  = s & 1;         // h write-parity

        // ---- B fragments: kt 0,1 = h hi/lo; kt 2 = x hi/lo (g16==0) else zeros ----
        bf16x8 bhi[3], blo[3];
#pragma unroll
        for (int kt = 0; kt < 2; ++kt) {
            bhi[kt] = *(const bf16x8*)&lds_hhi[rb][bcol][kt * 32 + g16 * 8];
            blo[kt] = *(const bf16x8*)&lds_hlo[rb][bcol][kt * 32 + g16 * 8];
        }
        {
            const short* ph = (g16 == 0) ? &lds_xbh[buf][cs][bcol][0] : &lds_xzero[0];
            const short* pl = (g16 == 0) ? &lds_xbl[buf][cs][bcol][0] : &lds_xzero[0];
            bhi[2] = *(const bf16x8*)ph;
            blo[2] = *(const bf16x8*)pl;
        }

        // ---- MFMA: 3 kt x 3-pass hi/lo, 4 independent acc chains ----
        f32x4 acc[4] = {{0,0,0,0},{0,0,0,0},{0,0,0,0},{0,0,0,0}};
#pragma unroll
        for (int kt = 0; kt < 3; ++kt) {
#pragma unroll
            for (int g = 0; g < 4; ++g)
                acc[g] = __builtin_amdgcn_mfma_f32_16x16x32_bf16(a_hi[g][kt], bhi[kt], acc[g], 0, 0, 0);
#pragma unroll
            for (int g = 0; g < 4; ++g)
                acc[g] = __builtin_amdgcn_mfma_f32_16x16x32_bf16(a_lo[g][kt], bhi[kt], acc[g], 0, 0, 0);
#pragma unroll
            for (int g = 0; g < 4; ++g)
                acc[g] = __builtin_amdgcn_mfma_f32_16x16x32_bf16(a_hi[g][kt], blo[kt], acc[g], 0, 0, 0);
        }

        // ---- activation fully in-register: 4 units per lane ----
        float hv[4];
#pragma unroll
        for (int r = 0; r < 4; ++r) {
            float ig = sigm(acc[0][r]);
            float fg = sigm(acc[1][r]);
            float gg = tanh_f(acc[2][r]);
            float og = sigm(acc[3][r]);
            c_reg[r] = fg * c_reg[r] + ig * gg;
            hv[r] = og * tanh_f(c_reg[r]);
        }

        // ---- publish h: writer lanes only (cols 0..3), packed b64 hi + b64 lo ----
        if ((lane & 12) == 0) {
            bf16x4 phi, plo;
#pragma unroll
            for (int r = 0; r < 4; ++r) {
                short hi = f2bf(hv[r]);
                phi[r] = hi;
                plo[r] = f2bf(hv[r] - bf2f(hi));
            }
            *(bf16x4*)&lds_hhi[wb][bcol][u0] = phi;
            *(bf16x4*)&lds_hlo[wb][bcol][u0] = plo;
            if (s + 1 == SEQ) {
                f32x4 hq, cq;
#pragma unroll
                for (int r = 0; r < 4; ++r) { hq[r] = hv[r]; cq[r] = c_reg[r]; }
                *(f32x4*)&lds_hf[bcol][u0] = hq;
                *(f32x4*)&lds_cf[bcol][u0] = cq;
            }
        }

        // ---- prefetch next x chunk (bf16 hi/lo split) ----
        if (cs == 0 && s + CHUNK < SEQ) {
            const int nbuf = buf ^ 1;
            const int s0n  = s + CHUNK;
            for (int i = tid; i < NB * CHUNK * 8; i += 256) {
                int b = i >> 8;
                int r = i & 255;
                int ss = r >> 3;
                int k = r & 7;
                float v = (k < 7) ? x[((size_t)(b0 + b) * SEQ + (s0n + ss)) * INDIM + k] : 1.0f;
                short hi = f2bf(v);
                lds_xbh[nbuf][ss][b][k] = hi;
                lds_xbl[nbuf][ss][b][k] = f2bf(v - bf2f(hi));
            }
        }
        __syncthreads();   // h[wb] published for next step
    }
    // lds_hf/lds_cf hold h_enc/c_enc in (b, j) layout

    // ====== decoder gbase = b + h_enc @ dW_hh.T (fp32, one-time) ======
    {
        const int row = wid * HDIM + lane;
        float4 dwhh[16];
#pragma unroll
        for (int m4 = 0; m4 < 16; ++m4)
            dwhh[m4] = *reinterpret_cast<const float4*>(&dWhh[row * HDIM + m4 * 4]);
        const float dbias = dbih[row] + dbhh[row];

        float acc[NB];
#pragma unroll
        for (int b = 0; b < NB; ++b) acc[b] = dbias;
#pragma unroll
        for (int m4 = 0; m4 < 16; ++m4) {
            const float4 w = dwhh[m4];
            float4 hv4[NB];
#pragma unroll
            for (int b = 0; b < NB; ++b)
                hv4[b] = *reinterpret_cast<const float4*>(&lds_hf[b][m4 * 4]);
#pragma unroll
            for (int b = 0; b < NB; ++b) acc[b] = fmaf(hv4[b].x, w.x, acc[b]);
#pragma unroll
            for (int b = 0; b < NB; ++b) acc[b] = fmaf(hv4[b].y, w.y, acc[b]);
#pragma unroll
            for (int b = 0; b < NB; ++b) acc[b] = fmaf(hv4[b].z, w.z, acc[b]);
#pragma unroll
            for (int b = 0; b < NB; ++b) acc[b] = fmaf(hv4[b].w, w.w, acc[b]);
        }
#pragma unroll
        for (int b = 0; b < NB; ++b) lds_g[b][row] = acc[b];
    }
    __syncthreads();

    // ================= decoder: wave = one batch, lane = unit =================
    {
        const int b = wid, j = lane;
        const float c_e = lds_cf[b][j];
        const float gb0 = lds_g[b][j];
        const float gb1 = lds_g[b][HDIM + j];
        const float gb2 = lds_g[b][2 * HDIM + j];
        const float gb3 = lds_g[b][3 * HDIM + j];

        const float w00 = dWih[(0 * HDIM + j) * QDIM + 0], w01 = dWih[(0 * HDIM + j) * QDIM + 1], w02 = dWih[(0 * HDIM + j) * QDIM + 2];
        const float w10 = dWih[(1 * HDIM + j) * QDIM + 0], w11 = dWih[(1 * HDIM + j) * QDIM + 1], w12 = dWih[(1 * HDIM + j) * QDIM + 2];
        const float w20 = dWih[(2 * HDIM + j) * QDIM + 0], w21 = dWih[(2 * HDIM + j) * QDIM + 1], w22 = dWih[(2 * HDIM + j) * QDIM + 2];
        const float w30 = dWih[(3 * HDIM + j) * QDIM + 0], w31 = dWih[(3 * HDIM + j) * QDIM + 1], w32 = dWih[(3 * HDIM + j) * QDIM + 2];
        const float ow0 = oW[0 * HDIM + j], ow1 = oW[1 * HDIM + j], ow2 = oW[2 * HDIM + j];
        const float ob0 = obv[0], ob1 = obv[1], ob2 = obv[2];

        float y0 = 0.0f, y1 = 0.0f, y2 = 0.0f;
        float* outp = out + (size_t)(b0 + b) * TDEC * QDIM;

        for (int t = 0; t < TDEC; ++t) {
            float g0 = gb0 + y0 * w00 + y1 * w01 + y2 * w02;
            float g1 = gb1 + y0 * w10 + y1 * w11 + y2 * w12;
            float g2 = gb2 + y0 * w20 + y1 * w21 + y2 * w22;
            float g3 = gb3 + y0 * w30 + y1 * w31 + y2 * w32;
            float ig = sigm(g0), fg = sigm(g1), gg = tanh_f(g2), og = sigm(g3);
            float c = fg * c_e + ig * gg;
            float h = og * tanh_f(c);
            float r0 = h * ow0, r1 = h * ow1, r2 = h * ow2;
#pragma unroll
            for (int d = 1; d < 64; d <<= 1) {
                r0 += __shfl_xor(r0, d);
                r1 += __shfl_xor(r1, d);
                r2 += __shfl_xor(r2, d);
            }
            y0 = r0 + ob0;
            y1 = r1 + ob1;
            y2 = r2 + ob2;
            if (j < QDIM) outp[t * QDIM + j] = (j == 0) ? y0 : (j == 1) ? y1 : y2;
        }
    }
}

extern "C" void kernel_launch(void* const* d_in, const int* in_sizes, int n_in,
                              void* d_out, int out_size, void* d_ws, size_t ws_size,
                              hipStream_t stream) {
    (void)in_sizes; (void)n_in; (void)d_ws; (void)ws_size; (void)out_size;
    const float* x    = (const float*)d_in[0];
    const float* eWih = (const float*)d_in[1];
    const float* eWhh = (const float*)d_in[2];
    const float* ebih = (const float*)d_in[3];
    const float* ebhh = (const float*)d_in[4];
    const float* dWih = (const float*)d_in[5];
    const float* dWhh = (const float*)d_in[6];
    const float* dbih = (const float*)d_in[7];
    const float* dbhh = (const float*)d_in[8];
    const float* oW   = (const float*)d_in[9];
    const float* obv  = (const float*)d_in[10];
    float* out = (float*)d_out;

    const int B = 2048;
    dim3 grid(B / NB), block(256);
    enc_dec_kernel<<<grid, block, 0, stream>>>(x, eWih, eWhh, ebih, ebhh,
                                               dWih, dWhh, dbih, dbhh, oW, obv, out);
}

// Round 10
// 697.027 us; speedup vs baseline: 1.1349x; 1.1349x over previous
//
#include <hip/hip_runtime.h>

#define HDIM  64
#define INDIM 7
#define QDIM  3
#define TDEC  288
#define SEQ   512
#define NBT   8        // batches per block: group A = 0..3, group B = 4..7
#define CHUNK 32       // x timesteps staged per LDS chunk
#define HPAD  68       // fp32 h row stride (decoder handoff)
#define GPAD  264      // lds_g row stride: <=2-way bank aliasing
#define HBST  80       // bf16 h row stride in shorts (160B)

typedef __attribute__((ext_vector_type(8))) short bf16x8;   // 8 bf16 in 4 VGPRs
typedef __attribute__((ext_vector_type(4))) float f32x4;

__device__ __forceinline__ float fast_rcp(float x) { return __builtin_amdgcn_rcpf(x); }
__device__ __forceinline__ float sigm(float x) { return fast_rcp(1.0f + __expf(-x)); }
__device__ __forceinline__ float tanh_f(float x) {
    float xx = fminf(fmaxf(x, -15.0f), 15.0f);
    float e = __expf(2.0f * xx);
    return (e - 1.0f) * fast_rcp(e + 1.0f);
}
// round-to-nearest-even fp32 -> bf16 bits
__device__ __forceinline__ short f2bf(float f) {
    union { float f; unsigned u; } v; v.f = f;
    unsigned r = (v.u + 0x7fffu + ((v.u >> 16) & 1u)) >> 16;
    return (short)r;
}
__device__ __forceinline__ float bf2f(short s) {
    union { unsigned u; float f; } v; v.u = ((unsigned)(unsigned short)s) << 16;
    return v.f;
}

// R10: two-group software pipeline. 512 threads = 8 waves; group A = waves
// 0-3 (batches 0-3), group B = waves 4-7 (batches 4-7), B lags A by half a
// step. Per iteration:
//   I0: waves 0-3 MFMA_A(s)          | waves 4-7 act_B(s-1)      ; barrier
//   I1: waves 0-3 act_A(s)           | waves 4-7 MFMA_B(s)       ; barrier
// Each SIMD hosts one MFMA-phase wave + one act-phase wave every interval ->
// MFMA pipe and VALU/trans pipe both fed; each group's dep chain hides under
// the other's work. 3-pass hi/lo bf16 MFMA (~fp32), producer-side h split,
// single-buffered h/g (phases barrier-separated), c in registers end-to-end.
__global__ __launch_bounds__(512, 2)
void enc_dec_kernel(const float* __restrict__ x,
                    const float* __restrict__ eWih, const float* __restrict__ eWhh,
                    const float* __restrict__ ebih, const float* __restrict__ ebhh,
                    const float* __restrict__ dWih, const float* __restrict__ dWhh,
                    const float* __restrict__ dbih, const float* __restrict__ dbhh,
                    const float* __restrict__ oW,   const float* __restrict__ obv,
                    float* __restrict__ out)
{
    __shared__ __align__(16) short lds_hhi[NBT][HBST];   // h hi bf16 (cols 0..63)
    __shared__ __align__(16) short lds_hlo[NBT][HBST];   // h lo bf16
    __shared__ __align__(16) float lds_hf[NBT][HPAD];    // fp32 h_enc (final step)
    __shared__ __align__(16) float lds_g[NBT][GPAD];     // pre-gates per group
    __shared__ __align__(16) float lds_x[2][NBT][CHUNK][8];  // fp32 x, pad zeroed

    const int tid   = threadIdx.x;
    const int lane  = tid & 63;
    const int wid   = tid >> 6;          // 0..7
    const int grp   = wid >> 2;          // 0 = A, 1 = B
    const int gate  = wid & 3;           // this wave's gate for MFMA role
    const int gslot = grp * 4;           // batch-slot base of this wave's group
    const int b0    = blockIdx.x * NBT;

    // ---- A-fragments: Whh rows of gate `gate`, hi/lo bf16 (shared by groups) ----
    bf16x8 a_hi[4][2], a_lo[4][2];
    {
        const int m = lane & 15, g16 = lane >> 4;
#pragma unroll
        for (int Mt = 0; Mt < 4; ++Mt) {
#pragma unroll
            for (int kt = 0; kt < 2; ++kt) {
                const float* p = eWhh + (size_t)(gate * 64 + Mt * 16 + m) * HDIM + kt * 32 + g16 * 8;
                f32x4 v0 = *(const f32x4*)p;
                f32x4 v1 = *(const f32x4*)(p + 4);
#pragma unroll
                for (int e = 0; e < 4; ++e) {
                    short hi = f2bf(v0[e]);
                    a_hi[Mt][kt][e] = hi;
                    a_lo[Mt][kt][e] = f2bf(v0[e] - bf2f(hi));
                }
#pragma unroll
                for (int e = 0; e < 4; ++e) {
                    short hi = f2bf(v1[e]);
                    a_hi[Mt][kt][4 + e] = hi;
                    a_lo[Mt][kt][4 + e] = f2bf(v1[e] - bf2f(hi));
                }
            }
        }
    }

    // ---- act constants: rows g*64 + lane (same for both groups) ----
    float wih_r[4][7];
    float bias_r[4];
#pragma unroll
    for (int g = 0; g < 4; ++g) {
        const int r = g * 64 + lane;
#pragma unroll
        for (int k = 0; k < 7; ++k) wih_r[g][k] = eWih[r * INDIM + k];
        bias_r[g] = ebih[r] + ebhh[r];
    }

    // ---- init: h = 0 for all 8 batch slots; c = 0 ----
    lds_hhi[wid][lane] = 0;
    lds_hlo[wid][lane] = 0;
    float c_reg = 0.0f;     // c for (batch slot = wid, unit = lane)

    // ---- load x chunk 0 (fp32, pad lane zeroed) ----
    for (int i = tid; i < NBT * CHUNK * 8; i += 512) {
        int b = i >> 8;          // CHUNK*8 == 256 per batch
        int r = i & 255;
        int s = r >> 3;
        int k = r & 7;
        float v = 0.0f;
        if (k < 7) v = x[((size_t)(b0 + b) * SEQ + s) * INDIM + k];
        lds_x[0][b][s][k] = v;
    }
    __syncthreads();

    // ---- role bodies ----
    auto mfma_role = [&]() {
        const int bb  = gslot + (lane & 3);
        const int g16 = lane >> 4;
        bf16x8 bhi[2], blo[2];
#pragma unroll
        for (int kt = 0; kt < 2; ++kt) {
            bhi[kt] = *(const bf16x8*)&lds_hhi[bb][kt * 32 + g16 * 8];
            blo[kt] = *(const bf16x8*)&lds_hlo[bb][kt * 32 + g16 * 8];
        }
        f32x4 acc[4] = {{0,0,0,0},{0,0,0,0},{0,0,0,0},{0,0,0,0}};
#pragma unroll
        for (int kt = 0; kt < 2; ++kt) {
#pragma unroll
            for (int Mt = 0; Mt < 4; ++Mt)
                acc[Mt] = __builtin_amdgcn_mfma_f32_16x16x32_bf16(a_hi[Mt][kt], bhi[kt], acc[Mt], 0, 0, 0);
#pragma unroll
            for (int Mt = 0; Mt < 4; ++Mt)
                acc[Mt] = __builtin_amdgcn_mfma_f32_16x16x32_bf16(a_lo[Mt][kt], bhi[kt], acc[Mt], 0, 0, 0);
#pragma unroll
            for (int Mt = 0; Mt < 4; ++Mt)
                acc[Mt] = __builtin_amdgcn_mfma_f32_16x16x32_bf16(a_hi[Mt][kt], blo[kt], acc[Mt], 0, 0, 0);
        }
        if ((lane & 12) == 0) {
#pragma unroll
            for (int Mt = 0; Mt < 4; ++Mt)
                *(f32x4*)&lds_g[bb][gate * 64 + Mt * 16 + g16 * 4] = acc[Mt];
        }
    };

    auto act_role = [&](int ss) {
        const int cs1 = ss & (CHUNK - 1);
        const int bx  = (ss >> 5) & 1;
        f32x4 x0 = *(const f32x4*)&lds_x[bx][wid][cs1][0];
        f32x4 x1 = *(const f32x4*)&lds_x[bx][wid][cs1][4];
        float pre[4];
#pragma unroll
        for (int g = 0; g < 4; ++g) {
            float p = lds_g[wid][g * 64 + lane] + bias_r[g];
            p += x0[0] * wih_r[g][0] + x0[1] * wih_r[g][1] + x0[2] * wih_r[g][2]
               + x0[3] * wih_r[g][3] + x1[0] * wih_r[g][4] + x1[1] * wih_r[g][5]
               + x1[2] * wih_r[g][6];
            pre[g] = p;
        }
        float ig = sigm(pre[0]), fg = sigm(pre[1]), gg = tanh_f(pre[2]), og = sigm(pre[3]);
        c_reg = fg * c_reg + ig * gg;
        float h = og * tanh_f(c_reg);
        short hi = f2bf(h);
        lds_hhi[wid][lane] = hi;
        lds_hlo[wid][lane] = f2bf(h - bf2f(hi));
        if (ss == SEQ - 1) lds_hf[wid][lane] = h;
    };

    // ================= encoder: pipelined, 2 intervals per step =================
    for (int s = 0; s < SEQ; ++s) {
        // ---- I0: MFMA_A(s)  ||  act_B(s-1) ----
        if (grp == 0) mfma_role();
        else if (s > 0) act_role(s - 1);
        __syncthreads();

        // ---- I1: act_A(s)  ||  MFMA_B(s) ----
        if (grp == 0) act_role(s);
        else mfma_role();

        // ---- prefetch next x chunk ----
        if ((s & (CHUNK - 1)) == 0 && s + CHUNK < SEQ) {
            const int nbuf = ((s >> 5) & 1) ^ 1;
            const int s0n  = s + CHUNK;
            for (int i = tid; i < NBT * CHUNK * 8; i += 512) {
                int b = i >> 8;
                int r = i & 255;
                int ss2 = r >> 3;
                int k = r & 7;
                float v = 0.0f;
                if (k < 7) v = x[((size_t)(b0 + b) * SEQ + (s0n + ss2)) * INDIM + k];
                lds_x[nbuf][b][ss2][k] = v;
            }
        }
        __syncthreads();
    }
    // ---- epilogue: finish group B's last step ----
    if (grp == 1) act_role(SEQ - 1);
    __syncthreads();
    // lds_hf = h_enc (all 8 slots); c_reg (thread (wid,lane)) = c_enc

    // ====== decoder gbase = b + h_enc @ dW_hh.T (fp32, one-time) ======
    {
        const int row = tid & 255;        // gate-matrix row
        const int gh  = tid >> 8;         // 0 -> batches 0-3, 1 -> batches 4-7
        float4 dwhh[16];
#pragma unroll
        for (int m4 = 0; m4 < 16; ++m4)
            dwhh[m4] = *reinterpret_cast<const float4*>(&dWhh[row * HDIM + m4 * 4]);
        const float dbias = dbih[row] + dbhh[row];

        float accd[4];
#pragma unroll
        for (int b = 0; b < 4; ++b) accd[b] = dbias;
#pragma unroll
        for (int m4 = 0; m4 < 16; ++m4) {
            const float4 w = dwhh[m4];
            float4 hv[4];
#pragma unroll
            for (int b = 0; b < 4; ++b)
                hv[b] = *reinterpret_cast<const float4*>(&lds_hf[gh * 4 + b][m4 * 4]);
#pragma unroll
            for (int b = 0; b < 4; ++b) accd[b] = fmaf(hv[b].x, w.x, accd[b]);
#pragma unroll
            for (int b = 0; b < 4; ++b) accd[b] = fmaf(hv[b].y, w.y, accd[b]);
#pragma unroll
            for (int b = 0; b < 4; ++b) accd[b] = fmaf(hv[b].z, w.z, accd[b]);
#pragma unroll
            for (int b = 0; b < 4; ++b) accd[b] = fmaf(hv[b].w, w.w, accd[b]);
        }
#pragma unroll
        for (int b = 0; b < 4; ++b) lds_g[gh * 4 + b][row] = accd[b];
    }
    __syncthreads();

    // ================= decoder: wave = one batch (8 waves, 8 batches) =================
    {
        const int b = wid, j = lane;
        const float c_e = c_reg;          // c_enc for (batch wid, unit lane)
        const float gb0 = lds_g[b][j];
        const float gb1 = lds_g[b][HDIM + j];
        const float gb2 = lds_g[b][2 * HDIM + j];
        const float gb3 = lds_g[b][3 * HDIM + j];

        const float w00 = dWih[(0 * HDIM + j) * QDIM + 0], w01 = dWih[(0 * HDIM + j) * QDIM + 1], w02 = dWih[(0 * HDIM + j) * QDIM + 2];
        const float w10 = dWih[(1 * HDIM + j) * QDIM + 0], w11 = dWih[(1 * HDIM + j) * QDIM + 1], w12 = dWih[(1 * HDIM + j) * QDIM + 2];
        const float w20 = dWih[(2 * HDIM + j) * QDIM + 0], w21 = dWih[(2 * HDIM + j) * QDIM + 1], w22 = dWih[(2 * HDIM + j) * QDIM + 2];
        const float w30 = dWih[(3 * HDIM + j) * QDIM + 0], w31 = dWih[(3 * HDIM + j) * QDIM + 1], w32 = dWih[(3 * HDIM + j) * QDIM + 2];
        const float ow0 = oW[0 * HDIM + j], ow1 = oW[1 * HDIM + j], ow2 = oW[2 * HDIM + j];
        const float ob0 = obv[0], ob1 = obv[1], ob2 = obv[2];

        float y0 = 0.0f, y1 = 0.0f, y2 = 0.0f;
        float* outp = out + (size_t)(b0 + b) * TDEC * QDIM;

        for (int t = 0; t < TDEC; ++t) {
            float g0 = gb0 + y0 * w00 + y1 * w01 + y2 * w02;
            float g1 = gb1 + y0 * w10 + y1 * w11 + y2 * w12;
            float g2 = gb2 + y0 * w20 + y1 * w21 + y2 * w22;
            float g3 = gb3 + y0 * w30 + y1 * w31 + y2 * w32;
            float ig = sigm(g0), fg = sigm(g1), gg = tanh_f(g2), og = sigm(g3);
            float c = fg * c_e + ig * gg;
            float h = og * tanh_f(c);
            float r0 = h * ow0, r1 = h * ow1, r2 = h * ow2;
#pragma unroll
            for (int d = 1; d < 64; d <<= 1) {
                r0 += __shfl_xor(r0, d);
                r1 += __shfl_xor(r1, d);
                r2 += __shfl_xor(r2, d);
            }
            y0 = r0 + ob0;
            y1 = r1 + ob1;
            y2 = r2 + ob2;
            if (j < QDIM) outp[t * QDIM + j] = (j == 0) ? y0 : (j == 1) ? y1 : y2;
        }
    }
}

extern "C" void kernel_launch(void* const* d_in, const int* in_sizes, int n_in,
                              void* d_out, int out_size, void* d_ws, size_t ws_size,
                              hipStream_t stream) {
    (void)in_sizes; (void)n_in; (void)d_ws; (void)ws_size; (void)out_size;
    const float* x    = (const float*)d_in[0];
    const float* eWih = (const float*)d_in[1];
    const float* eWhh = (const float*)d_in[2];
    const float* ebih = (const float*)d_in[3];
    const float* ebhh = (const float*)d_in[4];
    const float* dWih = (const float*)d_in[5];
    const float* dWhh = (const float*)d_in[6];
    const float* dbih = (const float*)d_in[7];
    const float* dbhh = (const float*)d_in[8];
    const float* oW   = (const float*)d_in[9];
    const float* obv  = (const float*)d_in[10];
    float* out = (float*)d_out;

    const int B = 2048;
    dim3 grid(B / NBT), block(512);
    enc_dec_kernel<<<grid, block, 0, stream>>>(x, eWih, eWhh, ebih, ebhh,
                                               dWih, dWhh, dbih, dbhh, oW, obv, out);
}

// Round 11
// 524.637 us; speedup vs baseline: 1.5078x; 1.3286x over previous
//
#include <hip/hip_runtime.h>

#define HDIM  64
#define INDIM 7
#define QDIM  3
#define TDEC  288
#define SEQ   512
#define NB    4        // batches per block (grid 512, 2 blocks/CU)
#define CHUNK 32       // x timesteps staged per LDS chunk
#define HPAD  68       // fp32 h/c row stride (decoder handoff)
#define GPAD  264      // lds_g row stride (decoder gbase only)
#define HBST  80       // bf16 h row stride in shorts (160B)

typedef __attribute__((ext_vector_type(8))) short bf16x8;   // 8 bf16 in 4 VGPRs
typedef __attribute__((ext_vector_type(4))) float f32x4;

__device__ __forceinline__ float fast_rcp(float x) { return __builtin_amdgcn_rcpf(x); }
__device__ __forceinline__ float sigm(float x) { return fast_rcp(1.0f + __expf(-x)); }
__device__ __forceinline__ float tanh_f(float x) {
    float xx = fminf(fmaxf(x, -15.0f), 15.0f);
    float e = __expf(2.0f * xx);
    return (e - 1.0f) * fast_rcp(e + 1.0f);
}
// round-to-nearest-even fp32 -> bf16 bits
__device__ __forceinline__ short f2bf(float f) {
    union { float f; unsigned u; } v; v.f = f;
    unsigned r = (v.u + 0x7fffu + ((v.u >> 16) & 1u)) >> 16;
    return (short)r;
}
__device__ __forceinline__ float bf2f(short s) {
    union { unsigned u; float f; } v; v.u = ((unsigned)(unsigned short)s) << 16;
    return v.f;
}

// R11: one barrier per step, zero redistribution.
// Wave wid owns units [16*wid, 16*wid+16) as 4 M-tiles {g*64+wid*16}, g=0..3.
// With batch-replicated B columns, lane L's acc[g][r] = pre-act of gate g for
// (b = L&3, u = wid*16 + (L>>4)*4 + r). Lane L runs the act chain for exactly
// r = (L>>2)&3 -> every (b,u) covered once per wave, no shuffles (R8) and no
// redundancy (R9); the r-extraction is 12 v_cndmask. h published as bf16
// hi/lo scatter (2-way banks = free), parity double-buffered; ONE
// __syncthreads per step. 3-pass hi/lo MFMA (~fp32 precision) as in R5.
__global__ __launch_bounds__(256, 2)
void enc_dec_kernel(const float* __restrict__ x,
                    const float* __restrict__ eWih, const float* __restrict__ eWhh,
                    const float* __restrict__ ebih, const float* __restrict__ ebhh,
                    const float* __restrict__ dWih, const float* __restrict__ dWhh,
                    const float* __restrict__ dbih, const float* __restrict__ dbhh,
                    const float* __restrict__ oW,   const float* __restrict__ obv,
                    float* __restrict__ out)
{
    __shared__ __align__(16) short lds_hhi[2][NB][HBST];   // h hi bf16, parity dbuf
    __shared__ __align__(16) short lds_hlo[2][NB][HBST];   // h lo bf16
    __shared__ __align__(16) float lds_hf[NB][HPAD];       // fp32 h_enc (final step)
    __shared__ __align__(16) float lds_cf[NB][HPAD];       // fp32 c_enc (final step)
    __shared__ __align__(16) float lds_g[NB][GPAD];        // decoder gbase staging
    __shared__ __align__(16) float lds_x[2][NB][CHUNK][8]; // fp32 x, pad zeroed

    const int tid  = threadIdx.x;
    const int lane = tid & 63;
    const int wid  = tid >> 6;
    const int b0   = blockIdx.x * NB;

    // act assignment: lane L -> (b = L&3, u = wid*16 + (L>>4)*4 + ((L>>2)&3))
    const int b_act = lane & 3;
    const int rsel  = (lane >> 2) & 3;
    const int u_act = wid * 16 + (lane >> 4) * 4 + rsel;

    // ---- A-fragments: M-tiles g*64 + wid*16, rows + (lane&15); hi/lo bf16 ----
    bf16x8 a_hi[4][2], a_lo[4][2];
    {
        const int m = lane & 15, g16 = lane >> 4;
#pragma unroll
        for (int g = 0; g < 4; ++g) {
#pragma unroll
            for (int kt = 0; kt < 2; ++kt) {
                const float* p = eWhh + (size_t)(g * 64 + wid * 16 + m) * HDIM + kt * 32 + g16 * 8;
                f32x4 v0 = *(const f32x4*)p;
                f32x4 v1 = *(const f32x4*)(p + 4);
#pragma unroll
                for (int e = 0; e < 4; ++e) {
                    short hi = f2bf(v0[e]);
                    a_hi[g][kt][e] = hi;
                    a_lo[g][kt][e] = f2bf(v0[e] - bf2f(hi));
                }
#pragma unroll
                for (int e = 0; e < 4; ++e) {
                    short hi = f2bf(v1[e]);
                    a_hi[g][kt][4 + e] = hi;
                    a_lo[g][kt][4 + e] = f2bf(v1[e] - bf2f(hi));
                }
            }
        }
    }

    // ---- act constants for rows g*64 + u_act ----
    float wih_r[4][7];
    float bias_r[4];
#pragma unroll
    for (int g = 0; g < 4; ++g) {
        const int r = g * 64 + u_act;
#pragma unroll
        for (int k = 0; k < 7; ++k) wih_r[g][k] = eWih[r * INDIM + k];
        bias_r[g] = ebih[r] + ebhh[r];
    }

    // ---- init: step 0 reads parity buffer 1 ----
    lds_hhi[1][wid][lane] = 0;
    lds_hlo[1][wid][lane] = 0;
    float c_reg = 0.0f;          // c for (b_act, u_act)

    // ---- load x chunk 0 ----
    for (int i = tid; i < NB * CHUNK * 8; i += 256) {
        int b = i >> 8;          // CHUNK*8 == 256
        int r = i & 255;
        int s = r >> 3;
        int k = r & 7;
        float v = 0.0f;
        if (k < 7) v = x[((size_t)(b0 + b) * SEQ + s) * INDIM + k];
        lds_x[0][b][s][k] = v;
    }
    __syncthreads();

    // ================= encoder: 512 serial steps, ONE barrier each =================
    for (int s = 0; s < SEQ; ++s) {
        const int cs  = s & (CHUNK - 1);
        const int buf = (s >> 5) & 1;
        const int rb  = (s & 1) ^ 1;   // h read-parity
        const int wb  = s & 1;         // h write-parity

        // ---- B fragments: pure b128 reads of pre-split bf16 h ----
        bf16x8 bhi[2], blo[2];
        {
            const int bb = lane & 3, g16 = lane >> 4;
#pragma unroll
            for (int kt = 0; kt < 2; ++kt) {
                bhi[kt] = *(const bf16x8*)&lds_hhi[rb][bb][kt * 32 + g16 * 8];
                blo[kt] = *(const bf16x8*)&lds_hlo[rb][bb][kt * 32 + g16 * 8];
            }
        }

        // ---- MFMA: 3-pass hi/lo, 4 independent acc chains ----
        f32x4 acc[4] = {{0,0,0,0},{0,0,0,0},{0,0,0,0},{0,0,0,0}};
#pragma unroll
        for (int kt = 0; kt < 2; ++kt) {
#pragma unroll
            for (int g = 0; g < 4; ++g)
                acc[g] = __builtin_amdgcn_mfma_f32_16x16x32_bf16(a_hi[g][kt], bhi[kt], acc[g], 0, 0, 0);
#pragma unroll
            for (int g = 0; g < 4; ++g)
                acc[g] = __builtin_amdgcn_mfma_f32_16x16x32_bf16(a_lo[g][kt], bhi[kt], acc[g], 0, 0, 0);
#pragma unroll
            for (int g = 0; g < 4; ++g)
                acc[g] = __builtin_amdgcn_mfma_f32_16x16x32_bf16(a_hi[g][kt], blo[kt], acc[g], 0, 0, 0);
        }

        // ---- extract this lane's r-slot via cndmask (no LDS, no scratch) ----
        float pre[4];
#pragma unroll
        for (int g = 0; g < 4; ++g) {
            float s01 = (rsel & 1) ? acc[g][1] : acc[g][0];
            float s23 = (rsel & 1) ? acc[g][3] : acc[g][2];
            pre[g] = (rsel & 2) ? s23 : s01;
        }

        // ---- activation: one chain per lane, (b_act, u_act) ----
        {
            f32x4 x0 = *(const f32x4*)&lds_x[buf][b_act][cs][0];
            f32x4 x1 = *(const f32x4*)&lds_x[buf][b_act][cs][4];
#pragma unroll
            for (int g = 0; g < 4; ++g) {
                pre[g] += bias_r[g]
                        + x0[0] * wih_r[g][0] + x0[1] * wih_r[g][1] + x0[2] * wih_r[g][2]
                        + x0[3] * wih_r[g][3] + x1[0] * wih_r[g][4] + x1[1] * wih_r[g][5]
                        + x1[2] * wih_r[g][6];
            }
            float ig = sigm(pre[0]), fg = sigm(pre[1]), gg = tanh_f(pre[2]), og = sigm(pre[3]);
            c_reg = fg * c_reg + ig * gg;
            float h = og * tanh_f(c_reg);
            short hi = f2bf(h);
            lds_hhi[wb][b_act][u_act] = hi;
            lds_hlo[wb][b_act][u_act] = f2bf(h - bf2f(hi));
            if (s + 1 == SEQ) {
                lds_hf[b_act][u_act] = h;
                lds_cf[b_act][u_act] = c_reg;
            }
        }

        // ---- prefetch next x chunk ----
        if (cs == 0 && s + CHUNK < SEQ) {
            const int nbuf = buf ^ 1;
            const int s0n  = s + CHUNK;
            for (int i = tid; i < NB * CHUNK * 8; i += 256) {
                int b = i >> 8;
                int r = i & 255;
                int ss = r >> 3;
                int k = r & 7;
                float v = 0.0f;
                if (k < 7) v = x[((size_t)(b0 + b) * SEQ + (s0n + ss)) * INDIM + k];
                lds_x[nbuf][b][ss][k] = v;
            }
        }
        __syncthreads();   // h[wb] published for next step
    }
    // lds_hf/lds_cf hold h_enc/c_enc in (b, j) layout

    // ====== decoder gbase = b + h_enc @ dW_hh.T (fp32, one-time) ======
    {
        const int row = wid * HDIM + lane;
        float4 dwhh[16];
#pragma unroll
        for (int m4 = 0; m4 < 16; ++m4)
            dwhh[m4] = *reinterpret_cast<const float4*>(&dWhh[row * HDIM + m4 * 4]);
        const float dbias = dbih[row] + dbhh[row];

        float accd[NB];
#pragma unroll
        for (int b = 0; b < NB; ++b) accd[b] = dbias;
#pragma unroll
        for (int m4 = 0; m4 < 16; ++m4) {
            const float4 w = dwhh[m4];
            float4 hv[NB];
#pragma unroll
            for (int b = 0; b < NB; ++b)
                hv[b] = *reinterpret_cast<const float4*>(&lds_hf[b][m4 * 4]);
#pragma unroll
            for (int b = 0; b < NB; ++b) accd[b] = fmaf(hv[b].x, w.x, accd[b]);
#pragma unroll
            for (int b = 0; b < NB; ++b) accd[b] = fmaf(hv[b].y, w.y, accd[b]);
#pragma unroll
            for (int b = 0; b < NB; ++b) accd[b] = fmaf(hv[b].z, w.z, accd[b]);
#pragma unroll
            for (int b = 0; b < NB; ++b) accd[b] = fmaf(hv[b].w, w.w, accd[b]);
        }
#pragma unroll
        for (int b = 0; b < NB; ++b) lds_g[b][row] = accd[b];
    }
    __syncthreads();

    // ================= decoder: wave = one batch, lane = unit =================
    {
        const int b = wid, j = lane;
        const float c_e = lds_cf[b][j];
        const float gb0 = lds_g[b][j];
        const float gb1 = lds_g[b][HDIM + j];
        const float gb2 = lds_g[b][2 * HDIM + j];
        const float gb3 = lds_g[b][3 * HDIM + j];

        const float w00 = dWih[(0 * HDIM + j) * QDIM + 0], w01 = dWih[(0 * HDIM + j) * QDIM + 1], w02 = dWih[(0 * HDIM + j) * QDIM + 2];
        const float w10 = dWih[(1 * HDIM + j) * QDIM + 0], w11 = dWih[(1 * HDIM + j) * QDIM + 1], w12 = dWih[(1 * HDIM + j) * QDIM + 2];
        const float w20 = dWih[(2 * HDIM + j) * QDIM + 0], w21 = dWih[(2 * HDIM + j) * QDIM + 1], w22 = dWih[(2 * HDIM + j) * QDIM + 2];
        const float w30 = dWih[(3 * HDIM + j) * QDIM + 0], w31 = dWih[(3 * HDIM + j) * QDIM + 1], w32 = dWih[(3 * HDIM + j) * QDIM + 2];
        const float ow0 = oW[0 * HDIM + j], ow1 = oW[1 * HDIM + j], ow2 = oW[2 * HDIM + j];
        const float ob0 = obv[0], ob1 = obv[1], ob2 = obv[2];

        float y0 = 0.0f, y1 = 0.0f, y2 = 0.0f;
        float* outp = out + (size_t)(b0 + b) * TDEC * QDIM;

        for (int t = 0; t < TDEC; ++t) {
            float g0 = gb0 + y0 * w00 + y1 * w01 + y2 * w02;
            float g1 = gb1 + y0 * w10 + y1 * w11 + y2 * w12;
            float g2 = gb2 + y0 * w20 + y1 * w21 + y2 * w22;
            float g3 = gb3 + y0 * w30 + y1 * w31 + y2 * w32;
            float ig = sigm(g0), fg = sigm(g1), gg = tanh_f(g2), og = sigm(g3);
            float c = fg * c_e + ig * gg;
            float h = og * tanh_f(c);
            float r0 = h * ow0, r1 = h * ow1, r2 = h * ow2;
#pragma unroll
            for (int d = 1; d < 64; d <<= 1) {
                r0 += __shfl_xor(r0, d);
                r1 += __shfl_xor(r1, d);
                r2 += __shfl_xor(r2, d);
            }
            y0 = r0 + ob0;
            y1 = r1 + ob1;
            y2 = r2 + ob2;
            if (j < QDIM) outp[t * QDIM + j] = (j == 0) ? y0 : (j == 1) ? y1 : y2;
        }
    }
}

extern "C" void kernel_launch(void* const* d_in, const int* in_sizes, int n_in,
                              void* d_out, int out_size, void* d_ws, size_t ws_size,
                              hipStream_t stream) {
    (void)in_sizes; (void)n_in; (void)d_ws; (void)ws_size; (void)out_size;
    const float* x    = (const float*)d_in[0];
    const float* eWih = (const float*)d_in[1];
    const float* eWhh = (const float*)d_in[2];
    const float* ebih = (const float*)d_in[3];
    const float* ebhh = (const float*)d_in[4];
    const float* dWih = (const float*)d_in[5];
    const float* dWhh = (const float*)d_in[6];
    const float* dbih = (const float*)d_in[7];
    const float* dbhh = (const float*)d_in[8];
    const float* oW   = (const float*)d_in[9];
    const float* obv  = (const float*)d_in[10];
    float* out = (float*)d_out;

    const int B = 2048;
    dim3 grid(B / NB), block(256);
    enc_dec_kernel<<<grid, block, 0, stream>>>(x, eWih, eWhh, ebih, ebhh,
                                               dWih, dWhh, dbih, dbhh, oW, obv, out);
}